// Round 5
// baseline (162.994 us; speedup 1.0000x reference)
//
#include <hip/hip_runtime.h>
#include <hip/hip_bf16.h>
#include <stdint.h>

// Problem constants
#define NU 4000
#define NI 4000
#define RR 5
#define MM 256
#define OUTD 75
#define FDIM 128
#define KP 4096                 // padded K/row length
#define MPAD 4096               // padded row count (32 * 128)
#define HP_STRIDE 1024000       // 4000*256 elements per partial

typedef float f32x4 __attribute__((ext_vector_type(4)));
typedef int   i32x4 __attribute__((ext_vector_type(4)));
typedef short bf16x8 __attribute__((ext_vector_type(8)));

static __device__ __forceinline__ short f2b(float x) {
  __hip_bfloat16 h = __float2bfloat16(x);
  return (short)__builtin_bit_cast(unsigned short, h);
}
static __device__ __forceinline__ float b2f(short x) {
  unsigned int u = ((unsigned int)(unsigned short)x) << 16;
  return __builtin_bit_cast(float, u);
}
static __device__ __forceinline__ bf16x8 cvt8(f32x4 a, f32x4 b) {
  bf16x8 r;
  r[0] = f2b(a[0]); r[1] = f2b(a[1]); r[2] = f2b(a[2]); r[3] = f2b(a[3]);
  r[4] = f2b(b[0]); r[5] = f2b(b[1]); r[6] = f2b(b[2]); r[7] = f2b(b[3]);
  return r;
}

// ---------------------------------------------------------------------------
// K1: adj->int8 (both layouts, KP/MPAD zero-padded) + degree counts.
// grid (64,64) covers the full 4096x4096 padded region (pad written as 0).
// ---------------------------------------------------------------------------
__global__ __launch_bounds__(256) void k_trans(const int* __restrict__ adj,
                                               int8_t* __restrict__ a8,
                                               int8_t* __restrict__ a8t,
                                               int* __restrict__ Nu,
                                               int* __restrict__ Nv) {
  __shared__ int8_t lt[64][65];
  __shared__ int rowc[64];
  __shared__ int colp[4][64];
  const int i0 = blockIdx.x * 64;
  const int u0 = blockIdx.y * 64;
  const int t = threadIdx.x;
  const int w = t >> 6, lane = t & 63;
  int mycol = 0;
  for (int rep = 0; rep < 16; rep++) {
    const int r = rep * 4 + w;
    const int u = u0 + r, i = i0 + lane;
    int a = (u < NU && i < NI) ? adj[(size_t)u * NI + i] : 0;
    const int nz = (a > 0) ? 1 : 0;
    unsigned long long bal = __ballot(nz);
    if (lane == 0) rowc[r] = (int)__popcll(bal);
    mycol += nz;
    a8[(size_t)u * KP + i] = (int8_t)a;       // pad region written as 0
    lt[lane][r] = (int8_t)a;
  }
  colp[w][lane] = mycol;
  __syncthreads();
  for (int rep = 0; rep < 16; rep++) {
    const int r = rep * 4 + w;
    a8t[(size_t)(i0 + r) * KP + (u0 + lane)] = lt[r][lane];
  }
  if (t < 64) {
    const int cc = colp[0][t] + colp[1][t] + colp[2][t] + colp[3][t];
    if (i0 + t < NI && cc) atomicAdd(&Nv[i0 + t], cc);
    if (u0 + t < NU && rowc[t]) atomicAdd(&Nu[u0 + t], rowc[t]);
  }
}

// ---------------------------------------------------------------------------
// K2: P build (int8, x256 scale, KP-padded rows).
// ---------------------------------------------------------------------------
__global__ __launch_bounds__(256) void k_pbuild(const float* __restrict__ msgW,
                                                const int* __restrict__ Nu,
                                                const int* __restrict__ Nv,
                                                int8_t* __restrict__ Pu,
                                                int8_t* __restrict__ Pv) {
  const int b = blockIdx.x;                 // r*256 + m
  const float* src = msgW + (size_t)b * (NU + NI);
  for (int idx = threadIdx.x; idx < KP; idx += 256) {
    int8_t qv = 0, qu = 0;
    if (idx < NU) {
      const int cu = Nu[idx], cv = Nv[idx];
      const float su = cu > 0 ? rsqrtf((float)cu) * 256.0f : 0.f;
      const float sv = cv > 0 ? rsqrtf((float)cv) * 256.0f : 0.f;
      float xv = fminf(fmaxf(src[idx] * su, -127.f), 127.f);
      float xu = fminf(fmaxf(src[NU + idx] * sv, -127.f), 127.f);
      qv = (int8_t)__float2int_rn(xv);
      qu = (int8_t)__float2int_rn(xu);
    }
    Pv[(size_t)b * KP + idx] = qv;
    Pu[(size_t)b * KP + idx] = qu;
  }
}

// ---------------------------------------------------------------------------
// K3: LDS-free, barrier-free one-hot i8 MFMA GEMM (K=64 per MFMA).
//  - B fragments register-resident: double-buffered (b0/b1), 2-step prefetch.
//  - uniform s_waitcnt vmcnt(14) per step; no LDS, no lgkmcnt, no barriers.
//  - 512 thr = 8 waves (2 rowg x 4 colw), block tile 128r x 128c.
//  - grid 256 = 1 block/CU; bid&7 -> (side,bn,ks): per-XCD L2-resident P slice.
// ---------------------------------------------------------------------------
static __device__ __forceinline__ uint32_t ohp(uint32_t sel, int r) {
  // one-hot i8: result byte = 0x01 iff adj byte == r+1 (adj bytes are 0..5)
  const uint32_t TL[5] = {0x00000100u, 0x00010000u, 0x01000000u, 0u, 0u};
  const uint32_t TH[5] = {0u, 0u, 0u, 0x00000001u, 0x00000100u};
  return __builtin_amdgcn_perm(TH[r], TL[r], sel);
}

__global__ __launch_bounds__(512, 2) void k_gemm(const int8_t* __restrict__ Au,
                                                 const int8_t* __restrict__ Av,
                                                 const int8_t* __restrict__ Pu,
                                                 const int8_t* __restrict__ Pv,
                                                 const int* __restrict__ Nu,
                                                 const int* __restrict__ Nv,
                                                 __hip_bfloat16* __restrict__ Hp) {
  const int bid = blockIdx.x;
  const int side = bid & 1, bn = (bid >> 1) & 1, ks = (bid >> 2) & 1;
  const int bm = bid >> 3;                          // 0..31
  const int8_t* __restrict__ A8 = side ? Av : Au;
  const int8_t* __restrict__ P  = side ? Pv : Pu;
  const int* __restrict__ cnt = side ? Nv : Nu;
  const int kbeg = ks * 2048;
  const int kend = kbeg + 2048;                     // 32 steps of 64

  const int t = threadIdx.x;
  const int w = t >> 6, l = t & 63;
  const int l15 = l & 15, l4 = l >> 4;
  const int rowg = w >> 2, colw = w & 3;

  // fixed per-lane byte offsets (bases advance uniformly via +kk in SGPR)
  uint32_t voffA[4], voffB[10];
#pragma unroll
  for (int g = 0; g < 4; ++g)
    voffA[g] = (uint32_t)(bm * 128 + rowg * 64 + g * 16 + l15) * KP + l4 * 16;
#pragma unroll
  for (int r = 0; r < 5; ++r)
#pragma unroll
    for (int c = 0; c < 2; ++c)
      voffB[r * 2 + c] =
          (uint32_t)(r * 256 + bn * 128 + colw * 32 + c * 16 + l15) * KP + l4 * 16;

  i32x4 acc[4][2] = {};
  uint4 b0[10], b1[10], a0[4], a1[4];

#define LOADS(bb, aa, kpf) { _Pragma("unroll") \
  for (int i_ = 0; i_ < 10; ++i_) \
    bb[i_] = *(const uint4*)(P + voffB[i_] + (uint32_t)(kpf)); \
  _Pragma("unroll") \
  for (int g_ = 0; g_ < 4; ++g_) \
    aa[g_] = *(const uint4*)(A8 + voffA[g_] + (uint32_t)(kpf)); }

#define BODY(bb, aa, kk) { \
  asm volatile("s_waitcnt vmcnt(14)" ::: "memory"); \
  __builtin_amdgcn_sched_barrier(0); \
  __builtin_amdgcn_s_setprio(1); \
  _Pragma("unroll") \
  for (int r_ = 0; r_ < 5; ++r_) { \
    _Pragma("unroll") \
    for (int g_ = 0; g_ < 4; ++g_) { \
      uint4 af_; \
      af_.x = ohp(aa[g_].x, r_); af_.y = ohp(aa[g_].y, r_); \
      af_.z = ohp(aa[g_].z, r_); af_.w = ohp(aa[g_].w, r_); \
      const i32x4 a4_ = __builtin_bit_cast(i32x4, af_); \
      acc[g_][0] = __builtin_amdgcn_mfma_i32_16x16x64_i8( \
          a4_, __builtin_bit_cast(i32x4, bb[r_ * 2 + 0]), acc[g_][0], 0, 0, 0); \
      acc[g_][1] = __builtin_amdgcn_mfma_i32_16x16x64_i8( \
          a4_, __builtin_bit_cast(i32x4, bb[r_ * 2 + 1]), acc[g_][1], 0, 0, 0); \
    } } \
  __builtin_amdgcn_s_setprio(0); \
  __builtin_amdgcn_sched_barrier(0); \
  { const int kpf_ = ((kk) + 128 < kend) ? (kk) + 128 : kend - 64; \
    LOADS(bb, aa, kpf_) } \
  __builtin_amdgcn_sched_barrier(0); }

  // prologue: t0 -> (b0,a0), t1 -> (b1,a1); order pinned
  LOADS(b0, a0, kbeg)
  __builtin_amdgcn_sched_barrier(0);
  LOADS(b1, a1, kbeg + 64)
  __builtin_amdgcn_sched_barrier(0);

  for (int kk = kbeg; kk < kend; kk += 128) {
    BODY(b0, a0, kk)
    BODY(b1, a1, kk + 64)
  }

  // epilogue: scale by rsqrt(cnt)/256, store bf16 partial (relu deferred)
  __hip_bfloat16* hp = Hp + (size_t)(ks * 2 + side) * HP_STRIDE;
#pragma unroll
  for (int g = 0; g < 4; ++g) {
    const int rowb = bm * 128 + rowg * 64 + g * 16 + l4 * 4;
#pragma unroll
    for (int c = 0; c < 2; ++c) {
      const int ocol = bn * 128 + colw * 32 + c * 16 + l15;
#pragma unroll
      for (int q = 0; q < 4; ++q) {
        const int orow = rowb + q;
        if (orow < 4000) {
          const int cv = cnt[orow];
          const float s = cv > 0 ? rsqrtf((float)cv) * (1.0f / 256.0f) : 0.f;
          hp[(size_t)orow * 256 + ocol] = __float2bfloat16((float)acc[g][c][q] * s);
        }
      }
    }
  }
#undef BODY
#undef LOADS
}

// ---------------------------------------------------------------------------
// K4: fused stage 2 (MFMA). Hsum = relu(part[side] + part[side+2]).
//   F = relu(sf@W1^T + b1);  out = relu(Hsum@dW^T + F@W2^T)
// grid 250 = 2 sides x 125, block 128.
// ---------------------------------------------------------------------------
__global__ __launch_bounds__(128) void k_out(const __hip_bfloat16* __restrict__ Hp,
                                             const float* __restrict__ usf,
                                             const float* __restrict__ vsf,
                                             const float* __restrict__ dW,
                                             const float* __restrict__ uW1,
                                             const float* __restrict__ ub1,
                                             const float* __restrict__ uW2,
                                             const float* __restrict__ vW1,
                                             const float* __restrict__ vb1,
                                             const float* __restrict__ vW2,
                                             float* __restrict__ out) {
  const int bid = blockIdx.x;
  const int side = bid / 125, rb = bid % 125;
  const int t = threadIdx.x, w = t >> 6, l = t & 63;
  const int l15 = l & 15, l4 = l >> 4;
  const int r0 = rb * 32 + w * 16;
  const float* __restrict__ sf = side ? vsf : usf;
  const float* __restrict__ W1 = side ? vW1 : uW1;
  const float* __restrict__ b1 = side ? vb1 : ub1;
  const float* __restrict__ W2 = side ? vW2 : uW2;
  const __hip_bfloat16* __restrict__ hp = Hp + (size_t)side * HP_STRIDE;

  const int myrow = r0 + l15;

  __shared__ __hip_bfloat16 lf[2][16][72];

  // ---- Phase A: F = relu(sf @ W1^T + b1) ----
  f32x4 fA[4] = {};
#pragma unroll
  for (int kk = 0; kk < 128; kk += 32) {
    const float* ps = sf + (size_t)myrow * 128 + kk + 8 * l4;
    const bf16x8 af = cvt8(*(const f32x4*)ps, *(const f32x4*)(ps + 4));
#pragma unroll
    for (int c = 0; c < 4; ++c) {
      const float* pw = W1 + (size_t)(c * 16 + l15) * 128 + kk + 8 * l4;
      const bf16x8 bf = cvt8(*(const f32x4*)pw, *(const f32x4*)(pw + 4));
      fA[c] = __builtin_amdgcn_mfma_f32_16x16x32_bf16(af, bf, fA[c], 0, 0, 0);
    }
  }
#pragma unroll
  for (int c = 0; c < 4; ++c) {
    const float bv = b1[c * 16 + l15];
#pragma unroll
    for (int reg = 0; reg < 4; ++reg) {
      float v = fA[c][reg] + bv;
      lf[w][l4 * 4 + reg][c * 16 + l15] = __float2bfloat16(v > 0.f ? v : 0.f);
    }
  }
  __syncthreads();

  // ---- Phase B: out = relu(Hsum@dW^T + F@W2^T) ----
  f32x4 oA[5] = {};
  const __hip_bfloat16* hbase = hp + (size_t)myrow * 256 + 8 * l4;
#pragma unroll
  for (int kk = 0; kk < 256; kk += 32) {
    const bf16x8 q0 = *(const bf16x8*)(hbase + kk);
    const bf16x8 q1 = *(const bf16x8*)(hbase + 2 * HP_STRIDE + kk);
    bf16x8 af;
#pragma unroll
    for (int j = 0; j < 8; ++j) {
      float hv = b2f(q0[j]) + b2f(q1[j]);
      af[j] = f2b(hv > 0.f ? hv : 0.f);
    }
#pragma unroll
    for (int c = 0; c < 5; ++c) {
      int oc = c * 16 + l15; if (oc > 74) oc = 74;   // clamp, stores guarded
      const float* pd = dW + (size_t)oc * 256 + kk + 8 * l4;
      const bf16x8 bf = cvt8(*(const f32x4*)pd, *(const f32x4*)(pd + 4));
      oA[c] = __builtin_amdgcn_mfma_f32_16x16x32_bf16(af, bf, oA[c], 0, 0, 0);
    }
  }
#pragma unroll
  for (int kk = 0; kk < 64; kk += 32) {
    const bf16x8 af = *(const bf16x8*)(&lf[w][l15][kk + 8 * l4]);
#pragma unroll
    for (int c = 0; c < 5; ++c) {
      int oc = c * 16 + l15; if (oc > 74) oc = 74;
      const float* pw = W2 + (size_t)oc * 64 + kk + 8 * l4;
      const bf16x8 bf = cvt8(*(const f32x4*)pw, *(const f32x4*)(pw + 4));
      oA[c] = __builtin_amdgcn_mfma_f32_16x16x32_bf16(af, bf, oA[c], 0, 0, 0);
    }
  }
  float* po = out + (size_t)side * (4000 * 75);
#pragma unroll
  for (int c = 0; c < 5; ++c) {
    const int oc = c * 16 + l15;
    if (oc < 75) {
#pragma unroll
      for (int reg = 0; reg < 4; ++reg) {
        const int orow = r0 + l4 * 4 + reg;
        const float v = oA[c][reg];
        po[(size_t)orow * 75 + oc] = v > 0.f ? v : 0.f;
      }
    }
  }
}

// ---------------------------------------------------------------------------
extern "C" void kernel_launch(void* const* d_in, const int* in_sizes, int n_in,
                              void* d_out, int out_size, void* d_ws, size_t ws_size,
                              hipStream_t stream) {
  const int* adj = (const int*)d_in[0];
  const float* usf = (const float*)d_in[1];
  const float* vsf = (const float*)d_in[2];
  const float* msgW = (const float*)d_in[3];
  const float* dW = (const float*)d_in[4];
  const float* uW1 = (const float*)d_in[5];
  const float* ub1 = (const float*)d_in[6];
  const float* uW2 = (const float*)d_in[7];
  const float* vW1 = (const float*)d_in[8];
  const float* vb1 = (const float*)d_in[9];
  const float* vW2 = (const float*)d_in[10];
  float* out = (float*)d_out;

  char* w = (char*)d_ws;
  const size_t A_BYTES = (size_t)MPAD * KP;            // 16,777,216
  const size_t P_BYTES = (size_t)RR * MM * KP;         // 5,242,880 (int8)
  const size_t HP_BYTES = (size_t)4 * HP_STRIDE * 2;   // 8,192,000 (bf16)
  int* Nu = (int*)w;
  int* Nv = (int*)(w + 16384);
  int8_t* Au = (int8_t*)(w + 32768);
  int8_t* Av = Au + A_BYTES;
  int8_t* Pu = (int8_t*)(w + 32768 + 2 * A_BYTES);
  int8_t* Pv = Pu + P_BYTES;
  __hip_bfloat16* Hp = (__hip_bfloat16*)(w + 32768 + 2 * A_BYTES + 2 * P_BYTES);
  const size_t need = 32768 + 2 * A_BYTES + 2 * P_BYTES + HP_BYTES;  // 52,264,960
  if (ws_size < need) return;

  hipMemsetAsync(w, 0, 32768, stream);
  k_trans<<<dim3(64, 64), 256, 0, stream>>>(adj, Au, Av, Nu, Nv);
  k_pbuild<<<1280, 256, 0, stream>>>(msgW, Nu, Nv, Pu, Pv);
  k_gemm<<<256, 512, 0, stream>>>(Au, Av, Pu, Pv, Nu, Nv, Hp);
  k_out<<<250, 128, 0, stream>>>(Hp, usf, vsf, dW, uW1, ub1, uW2, vW1, vb1, vW2,
                                 out);
}

// Round 6
// 131.904 us; speedup vs baseline: 1.2357x; 1.2357x over previous
//
#include <hip/hip_runtime.h>
#include <hip/hip_bf16.h>
#include <stdint.h>

// Problem constants
#define NU 4000
#define NI 4000
#define RR 5
#define MM 256
#define OUTD 75
#define FDIM 128
#define KP 4096                 // padded K/row length
#define MPAD 4096               // padded row count (32 * 128)
#define HP_STRIDE 1024000       // 4000*256 elements per partial

typedef float f32x4 __attribute__((ext_vector_type(4)));
typedef int   i32x4 __attribute__((ext_vector_type(4)));
typedef short bf16x8 __attribute__((ext_vector_type(8)));

static __device__ __forceinline__ short f2b(float x) {
  __hip_bfloat16 h = __float2bfloat16(x);
  return (short)__builtin_bit_cast(unsigned short, h);
}
static __device__ __forceinline__ float b2f(short x) {
  unsigned int u = ((unsigned int)(unsigned short)x) << 16;
  return __builtin_bit_cast(float, u);
}
static __device__ __forceinline__ bf16x8 cvt8(f32x4 a, f32x4 b) {
  bf16x8 r;
  r[0] = f2b(a[0]); r[1] = f2b(a[1]); r[2] = f2b(a[2]); r[3] = f2b(a[3]);
  r[4] = f2b(b[0]); r[5] = f2b(b[1]); r[6] = f2b(b[2]); r[7] = f2b(b[3]);
  return r;
}

// ---------------------------------------------------------------------------
// K1: adj->int8 (both layouts, KP/MPAD zero-padded) + degree counts.
// ---------------------------------------------------------------------------
__global__ __launch_bounds__(256) void k_trans(const int* __restrict__ adj,
                                               int8_t* __restrict__ a8,
                                               int8_t* __restrict__ a8t,
                                               int* __restrict__ Nu,
                                               int* __restrict__ Nv) {
  __shared__ int8_t lt[64][65];
  __shared__ int rowc[64];
  __shared__ int colp[4][64];
  const int i0 = blockIdx.x * 64;
  const int u0 = blockIdx.y * 64;
  const int t = threadIdx.x;
  const int w = t >> 6, lane = t & 63;
  int mycol = 0;
  for (int rep = 0; rep < 16; rep++) {
    const int r = rep * 4 + w;
    const int u = u0 + r, i = i0 + lane;
    int a = (u < NU && i < NI) ? adj[(size_t)u * NI + i] : 0;
    const int nz = (a > 0) ? 1 : 0;
    unsigned long long bal = __ballot(nz);
    if (lane == 0) rowc[r] = (int)__popcll(bal);
    mycol += nz;
    a8[(size_t)u * KP + i] = (int8_t)a;       // pad region written as 0
    lt[lane][r] = (int8_t)a;
  }
  colp[w][lane] = mycol;
  __syncthreads();
  for (int rep = 0; rep < 16; rep++) {
    const int r = rep * 4 + w;
    a8t[(size_t)(i0 + r) * KP + (u0 + lane)] = lt[r][lane];
  }
  if (t < 64) {
    const int cc = colp[0][t] + colp[1][t] + colp[2][t] + colp[3][t];
    if (i0 + t < NI && cc) atomicAdd(&Nv[i0 + t], cc);
    if (u0 + t < NU && rowc[t]) atomicAdd(&Nu[u0 + t], rowc[t]);
  }
}

// ---------------------------------------------------------------------------
// K2: P build (int8, x256 scale, KP-padded rows).
// ---------------------------------------------------------------------------
__global__ __launch_bounds__(256) void k_pbuild(const float* __restrict__ msgW,
                                                const int* __restrict__ Nu,
                                                const int* __restrict__ Nv,
                                                int8_t* __restrict__ Pu,
                                                int8_t* __restrict__ Pv) {
  const int b = blockIdx.x;                 // r*256 + m
  const float* src = msgW + (size_t)b * (NU + NI);
  for (int idx = threadIdx.x; idx < KP; idx += 256) {
    int8_t qv = 0, qu = 0;
    if (idx < NU) {
      const int cu = Nu[idx], cv = Nv[idx];
      const float su = cu > 0 ? rsqrtf((float)cu) * 256.0f : 0.f;
      const float sv = cv > 0 ? rsqrtf((float)cv) * 256.0f : 0.f;
      float xv = fminf(fmaxf(src[idx] * su, -127.f), 127.f);
      float xu = fminf(fmaxf(src[NU + idx] * sv, -127.f), 127.f);
      qv = (int8_t)__float2int_rn(xv);
      qu = (int8_t)__float2int_rn(xu);
    }
    Pv[(size_t)b * KP + idx] = qv;
    Pu[(size_t)b * KP + idx] = qu;
  }
}

// ---------------------------------------------------------------------------
// K3: LDS-free, barrier-free one-hot i8 MFMA GEMM (K=64 per MFMA).
//  vs R5: __launch_bounds__(256,1) -> 512-VGPR budget (1 wave/SIMD), so the
//  register double-buffer actually fits; 8 row-groups (block tile 128x128,
//  4 waves x 32 cols) -> 80 MFMA/step/wave, arithmetic intensity doubled.
//  grid 256 = 1 block/CU; bid&7 -> (side,bn,ks): per-XCD L2-resident P slice.
// ---------------------------------------------------------------------------
static __device__ __forceinline__ uint32_t ohp(uint32_t sel, int r) {
  // one-hot i8: result byte = 0x01 iff adj byte == r+1 (adj bytes are 0..5)
  const uint32_t TL[5] = {0x00000100u, 0x00010000u, 0x01000000u, 0u, 0u};
  const uint32_t TH[5] = {0u, 0u, 0u, 0x00000001u, 0x00000100u};
  return __builtin_amdgcn_perm(TH[r], TL[r], sel);
}

__global__ __launch_bounds__(256, 1) void k_gemm(const int8_t* __restrict__ Au,
                                                 const int8_t* __restrict__ Av,
                                                 const int8_t* __restrict__ Pu,
                                                 const int8_t* __restrict__ Pv,
                                                 const int* __restrict__ Nu,
                                                 const int* __restrict__ Nv,
                                                 __hip_bfloat16* __restrict__ Hp) {
  const int bid = blockIdx.x;
  const int side = bid & 1, bn = (bid >> 1) & 1, ks = (bid >> 2) & 1;
  const int bm = bid >> 3;                          // 0..31
  const int8_t* __restrict__ A8 = side ? Av : Au;
  const int8_t* __restrict__ P  = side ? Pv : Pu;
  const int* __restrict__ cnt = side ? Nv : Nu;
  const int kbeg = ks * 2048;
  const int kend = kbeg + 2048;                     // 32 steps of 64

  const int t = threadIdx.x;
  const int w = t >> 6, l = t & 63;                 // w = col-wave 0..3
  const int l15 = l & 15, l4 = l >> 4;

  // fixed per-lane byte offsets (k advances via uniform +kk)
  uint32_t voffA[8], voffB[10];
#pragma unroll
  for (int g = 0; g < 8; ++g)
    voffA[g] = (uint32_t)(bm * 128 + g * 16 + l15) * KP + l4 * 16;
#pragma unroll
  for (int r = 0; r < 5; ++r)
#pragma unroll
    for (int c = 0; c < 2; ++c)
      voffB[r * 2 + c] =
          (uint32_t)(r * 256 + bn * 128 + w * 32 + c * 16 + l15) * KP + l4 * 16;

  i32x4 acc[8][2] = {};
  uint4 b0[10], b1[10], a0[8], a1[8];

#define LOADS(bb, aa, kpf) { _Pragma("unroll") \
  for (int i_ = 0; i_ < 10; ++i_) \
    bb[i_] = *(const uint4*)(P + voffB[i_] + (uint32_t)(kpf)); \
  _Pragma("unroll") \
  for (int g_ = 0; g_ < 8; ++g_) \
    aa[g_] = *(const uint4*)(A8 + voffA[g_] + (uint32_t)(kpf)); }

#define BODY(bb, aa, kk) { \
  asm volatile("s_waitcnt vmcnt(18)" ::: "memory"); \
  __builtin_amdgcn_sched_barrier(0); \
  _Pragma("unroll") \
  for (int r_ = 0; r_ < 5; ++r_) { \
    _Pragma("unroll") \
    for (int g_ = 0; g_ < 8; ++g_) { \
      uint4 af_; \
      af_.x = ohp(aa[g_].x, r_); af_.y = ohp(aa[g_].y, r_); \
      af_.z = ohp(aa[g_].z, r_); af_.w = ohp(aa[g_].w, r_); \
      const i32x4 a4_ = __builtin_bit_cast(i32x4, af_); \
      acc[g_][0] = __builtin_amdgcn_mfma_i32_16x16x64_i8( \
          a4_, __builtin_bit_cast(i32x4, bb[r_ * 2 + 0]), acc[g_][0], 0, 0, 0); \
      acc[g_][1] = __builtin_amdgcn_mfma_i32_16x16x64_i8( \
          a4_, __builtin_bit_cast(i32x4, bb[r_ * 2 + 1]), acc[g_][1], 0, 0, 0); \
    } } \
  __builtin_amdgcn_sched_barrier(0); \
  { const int kpf_ = ((kk) + 128 < kend) ? (kk) + 128 : kend - 64; \
    LOADS(bb, aa, kpf_) } \
  __builtin_amdgcn_sched_barrier(0); }

  // prologue: t0 -> (b0,a0), t1 -> (b1,a1); order pinned
  LOADS(b0, a0, kbeg)
  __builtin_amdgcn_sched_barrier(0);
  LOADS(b1, a1, kbeg + 64)
  __builtin_amdgcn_sched_barrier(0);

  for (int kk = kbeg; kk < kend; kk += 128) {
    BODY(b0, a0, kk)
    BODY(b1, a1, kk + 64)
  }

  // epilogue: scale by rsqrt(cnt)/256, store bf16 partial (relu deferred)
  __hip_bfloat16* hp = Hp + (size_t)(ks * 2 + side) * HP_STRIDE;
#pragma unroll
  for (int g = 0; g < 8; ++g) {
    const int rowb = bm * 128 + g * 16 + l4 * 4;
#pragma unroll
    for (int c = 0; c < 2; ++c) {
      const int ocol = bn * 128 + w * 32 + c * 16 + l15;
#pragma unroll
      for (int q = 0; q < 4; ++q) {
        const int orow = rowb + q;
        if (orow < 4000) {
          const int cv = cnt[orow];
          const float s = cv > 0 ? rsqrtf((float)cv) * (1.0f / 256.0f) : 0.f;
          hp[(size_t)orow * 256 + ocol] = __float2bfloat16((float)acc[g][c][q] * s);
        }
      }
    }
  }
#undef BODY
#undef LOADS
}

// ---------------------------------------------------------------------------
// K4: fused stage 2 (MFMA). Hsum = relu(part[side] + part[side+2]).
//   F = relu(sf@W1^T + b1);  out = relu(Hsum@dW^T + F@W2^T)
// grid 250 = 2 sides x 125, block 128.
// ---------------------------------------------------------------------------
__global__ __launch_bounds__(128) void k_out(const __hip_bfloat16* __restrict__ Hp,
                                             const float* __restrict__ usf,
                                             const float* __restrict__ vsf,
                                             const float* __restrict__ dW,
                                             const float* __restrict__ uW1,
                                             const float* __restrict__ ub1,
                                             const float* __restrict__ uW2,
                                             const float* __restrict__ vW1,
                                             const float* __restrict__ vb1,
                                             const float* __restrict__ vW2,
                                             float* __restrict__ out) {
  const int bid = blockIdx.x;
  const int side = bid / 125, rb = bid % 125;
  const int t = threadIdx.x, w = t >> 6, l = t & 63;
  const int l15 = l & 15, l4 = l >> 4;
  const int r0 = rb * 32 + w * 16;
  const float* __restrict__ sf = side ? vsf : usf;
  const float* __restrict__ W1 = side ? vW1 : uW1;
  const float* __restrict__ b1 = side ? vb1 : ub1;
  const float* __restrict__ W2 = side ? vW2 : uW2;
  const __hip_bfloat16* __restrict__ hp = Hp + (size_t)side * HP_STRIDE;

  const int myrow = r0 + l15;

  __shared__ __hip_bfloat16 lf[2][16][72];

  // ---- Phase A: F = relu(sf @ W1^T + b1) ----
  f32x4 fA[4] = {};
#pragma unroll
  for (int kk = 0; kk < 128; kk += 32) {
    const float* ps = sf + (size_t)myrow * 128 + kk + 8 * l4;
    const bf16x8 af = cvt8(*(const f32x4*)ps, *(const f32x4*)(ps + 4));
#pragma unroll
    for (int c = 0; c < 4; ++c) {
      const float* pw = W1 + (size_t)(c * 16 + l15) * 128 + kk + 8 * l4;
      const bf16x8 bf = cvt8(*(const f32x4*)pw, *(const f32x4*)(pw + 4));
      fA[c] = __builtin_amdgcn_mfma_f32_16x16x32_bf16(af, bf, fA[c], 0, 0, 0);
    }
  }
#pragma unroll
  for (int c = 0; c < 4; ++c) {
    const float bv = b1[c * 16 + l15];
#pragma unroll
    for (int reg = 0; reg < 4; ++reg) {
      float v = fA[c][reg] + bv;
      lf[w][l4 * 4 + reg][c * 16 + l15] = __float2bfloat16(v > 0.f ? v : 0.f);
    }
  }
  __syncthreads();

  // ---- Phase B: out = relu(Hsum@dW^T + F@W2^T) ----
  f32x4 oA[5] = {};
  const __hip_bfloat16* hbase = hp + (size_t)myrow * 256 + 8 * l4;
#pragma unroll
  for (int kk = 0; kk < 256; kk += 32) {
    const bf16x8 q0 = *(const bf16x8*)(hbase + kk);
    const bf16x8 q1 = *(const bf16x8*)(hbase + 2 * HP_STRIDE + kk);
    bf16x8 af;
#pragma unroll
    for (int j = 0; j < 8; ++j) {
      float hv = b2f(q0[j]) + b2f(q1[j]);
      af[j] = f2b(hv > 0.f ? hv : 0.f);
    }
#pragma unroll
    for (int c = 0; c < 5; ++c) {
      int oc = c * 16 + l15; if (oc > 74) oc = 74;   // clamp, stores guarded
      const float* pd = dW + (size_t)oc * 256 + kk + 8 * l4;
      const bf16x8 bf = cvt8(*(const f32x4*)pd, *(const f32x4*)(pd + 4));
      oA[c] = __builtin_amdgcn_mfma_f32_16x16x32_bf16(af, bf, oA[c], 0, 0, 0);
    }
  }
#pragma unroll
  for (int kk = 0; kk < 64; kk += 32) {
    const bf16x8 af = *(const bf16x8*)(&lf[w][l15][kk + 8 * l4]);
#pragma unroll
    for (int c = 0; c < 5; ++c) {
      int oc = c * 16 + l15; if (oc > 74) oc = 74;
      const float* pw = W2 + (size_t)oc * 64 + kk + 8 * l4;
      const bf16x8 bf = cvt8(*(const f32x4*)pw, *(const f32x4*)(pw + 4));
      oA[c] = __builtin_amdgcn_mfma_f32_16x16x32_bf16(af, bf, oA[c], 0, 0, 0);
    }
  }
  float* po = out + (size_t)side * (4000 * 75);
#pragma unroll
  for (int c = 0; c < 5; ++c) {
    const int oc = c * 16 + l15;
    if (oc < 75) {
#pragma unroll
      for (int reg = 0; reg < 4; ++reg) {
        const int orow = r0 + l4 * 4 + reg;
        const float v = oA[c][reg];
        po[(size_t)orow * 75 + oc] = v > 0.f ? v : 0.f;
      }
    }
  }
}

// ---------------------------------------------------------------------------
extern "C" void kernel_launch(void* const* d_in, const int* in_sizes, int n_in,
                              void* d_out, int out_size, void* d_ws, size_t ws_size,
                              hipStream_t stream) {
  const int* adj = (const int*)d_in[0];
  const float* usf = (const float*)d_in[1];
  const float* vsf = (const float*)d_in[2];
  const float* msgW = (const float*)d_in[3];
  const float* dW = (const float*)d_in[4];
  const float* uW1 = (const float*)d_in[5];
  const float* ub1 = (const float*)d_in[6];
  const float* uW2 = (const float*)d_in[7];
  const float* vW1 = (const float*)d_in[8];
  const float* vb1 = (const float*)d_in[9];
  const float* vW2 = (const float*)d_in[10];
  float* out = (float*)d_out;

  char* w = (char*)d_ws;
  const size_t A_BYTES = (size_t)MPAD * KP;            // 16,777,216
  const size_t P_BYTES = (size_t)RR * MM * KP;         // 5,242,880 (int8)
  const size_t HP_BYTES = (size_t)4 * HP_STRIDE * 2;   // 8,192,000 (bf16)
  int* Nu = (int*)w;
  int* Nv = (int*)(w + 16384);
  int8_t* Au = (int8_t*)(w + 32768);
  int8_t* Av = Au + A_BYTES;
  int8_t* Pu = (int8_t*)(w + 32768 + 2 * A_BYTES);
  int8_t* Pv = Pu + P_BYTES;
  __hip_bfloat16* Hp = (__hip_bfloat16*)(w + 32768 + 2 * A_BYTES + 2 * P_BYTES);
  const size_t need = 32768 + 2 * A_BYTES + 2 * P_BYTES + HP_BYTES;  // 52,264,960
  if (ws_size < need) return;

  hipMemsetAsync(w, 0, 32768, stream);
  k_trans<<<dim3(64, 64), 256, 0, stream>>>(adj, Au, Av, Nu, Nv);
  k_pbuild<<<1280, 256, 0, stream>>>(msgW, Nu, Nv, Pu, Pv);
  k_gemm<<<256, 256, 0, stream>>>(Au, Av, Pu, Pv, Nu, Nv, Hp);
  k_out<<<250, 128, 0, stream>>>(Hp, usf, vsf, dW, uW1, ub1, uW2, vW1, vb1, vW2,
                                 out);
}

// Round 7
// 116.784 us; speedup vs baseline: 1.3957x; 1.1295x over previous
//
#include <hip/hip_runtime.h>
#include <hip/hip_bf16.h>
#include <stdint.h>

// Problem constants
#define NU 4000
#define NI 4000
#define RR 5
#define MM 256
#define OUTD 75
#define FDIM 128
#define KP 4096                 // padded K length (P rows)
#define KPH 2048                // packed A row bytes (KP/2)
#define HP_STRIDE 1024000       // 4000*256 elements per partial

typedef float f32x4 __attribute__((ext_vector_type(4)));
typedef int   i32x4 __attribute__((ext_vector_type(4)));
typedef short bf16x8 __attribute__((ext_vector_type(8)));

static __device__ __forceinline__ short f2b(float x) {
  __hip_bfloat16 h = __float2bfloat16(x);
  return (short)__builtin_bit_cast(unsigned short, h);
}
static __device__ __forceinline__ float b2f(short x) {
  unsigned int u = ((unsigned int)(unsigned short)x) << 16;
  return __builtin_bit_cast(float, u);
}
static __device__ __forceinline__ bf16x8 cvt8(f32x4 a, f32x4 b) {
  bf16x8 r;
  r[0] = f2b(a[0]); r[1] = f2b(a[1]); r[2] = f2b(a[2]); r[3] = f2b(a[3]);
  r[4] = f2b(b[0]); r[5] = f2b(b[1]); r[6] = f2b(b[2]); r[7] = f2b(b[3]);
  return r;
}

// ---------------------------------------------------------------------------
// K1: adj -> nibble-packed int8 (both layouts; byte p = col 2p | col 2p+1 <<4)
//     + degree counts. grid (64,64), pad region written as 0.
// ---------------------------------------------------------------------------
__global__ __launch_bounds__(256) void k_trans(const int* __restrict__ adj,
                                               uint8_t* __restrict__ a8p,
                                               uint8_t* __restrict__ a8tp,
                                               int* __restrict__ Nu,
                                               int* __restrict__ Nv) {
  __shared__ int8_t lt[64][65];
  __shared__ int rowc[64];
  __shared__ int colp[4][64];
  const int i0 = blockIdx.x * 64;
  const int u0 = blockIdx.y * 64;
  const int t = threadIdx.x;
  const int w = t >> 6, lane = t & 63;
  int mycol = 0;
  for (int rep = 0; rep < 16; rep++) {
    const int r = rep * 4 + w;
    const int u = u0 + r, i = i0 + lane;
    int a = (u < NU && i < NI) ? adj[(size_t)u * NI + i] : 0;
    const int nz = (a > 0) ? 1 : 0;
    unsigned long long bal = __ballot(nz);
    if (lane == 0) rowc[r] = (int)__popcll(bal);
    mycol += nz;
    lt[lane][r] = (int8_t)a;
    const int nb = __shfl_down(a, 1);
    if (!(lane & 1))
      a8p[(size_t)u * KPH + (i0 >> 1) + (lane >> 1)] = (uint8_t)(a | (nb << 4));
  }
  colp[w][lane] = mycol;
  __syncthreads();
  for (int rep = 0; rep < 16; rep++) {
    const int r = rep * 4 + w;
    const int it = i0 + r;
    const int v = lt[r][lane];
    const int nb = __shfl_down(v, 1);
    if (!(lane & 1))
      a8tp[(size_t)it * KPH + (u0 >> 1) + (lane >> 1)] = (uint8_t)(v | (nb << 4));
  }
  if (t < 64) {
    const int cc = colp[0][t] + colp[1][t] + colp[2][t] + colp[3][t];
    if (i0 + t < NI && cc) atomicAdd(&Nv[i0 + t], cc);
    if (u0 + t < NU && rowc[t]) atomicAdd(&Nu[u0 + t], rowc[t]);
  }
}

// ---------------------------------------------------------------------------
// K2: P build (int8, x256 scale) with per-8 k-permutation matching the A
// nibble unpack order: storage s holds original k = (s&~7)|((s&3)<<1)|((s>>2)&1).
// ---------------------------------------------------------------------------
__global__ __launch_bounds__(256) void k_pbuild(const float* __restrict__ msgW,
                                                const int* __restrict__ Nu,
                                                const int* __restrict__ Nv,
                                                int8_t* __restrict__ Pu,
                                                int8_t* __restrict__ Pv) {
  const int b = blockIdx.x;                 // r*256 + m
  const float* src = msgW + (size_t)b * (NU + NI);
  for (int idx = threadIdx.x; idx < KP; idx += 256) {
    const int ko = (idx & ~7) | ((idx & 3) << 1) | ((idx >> 2) & 1);
    int8_t qv = 0, qu = 0;
    if (ko < NU) {
      const int cu = Nu[ko], cv = Nv[ko];
      const float su = cu > 0 ? rsqrtf((float)cu) * 256.0f : 0.f;
      const float sv = cv > 0 ? rsqrtf((float)cv) * 256.0f : 0.f;
      float xv = fminf(fmaxf(src[ko] * su, -127.f), 127.f);
      float xu = fminf(fmaxf(src[NU + ko] * sv, -127.f), 127.f);
      qv = (int8_t)__float2int_rn(xv);
      qu = (int8_t)__float2int_rn(xu);
    }
    Pv[(size_t)b * KP + idx] = qv;
    Pu[(size_t)b * KP + idx] = qu;
  }
}

// ---------------------------------------------------------------------------
// K3: one-hot i8 MFMA GEMM, 2-phase T3 schedule.
//  - B: LDS double-buffer 2x40KB (5r x 128c x 64k), gload_lds staged, 16B-unit
//    XOR swizzle (verified zero-conflict in R4): unit j' = j ^ ((col>>1)&3).
//  - A: nibble-packed, register double-buffered (uint2 per 16-row frag).
//  - 512 thr = 8 waves (2 rowg x 4 colw); tile 128r x 128c; BK=64; 16 steps.
//  - grid 512 = 2 blocks/CU; bid&7 -> XCD-pinned (side,bn,ks&1) P slice.
// ---------------------------------------------------------------------------
#define GLOAD_LDS(g, s) __builtin_amdgcn_global_load_lds( \
    (const __attribute__((address_space(1))) uint32_t*)(g), \
    (__attribute__((address_space(3))) uint32_t*)(s), 16, 0, 0)

static __device__ __forceinline__ uint32_t ohp(uint32_t sel, int r) {
  // one-hot i8: result byte = 0x01 iff input byte == r+1 (inputs 0..5)
  const uint32_t TL[5] = {0x00000100u, 0x00010000u, 0x01000000u, 0u, 0u};
  const uint32_t TH[5] = {0u, 0u, 0u, 0x00000001u, 0x00000100u};
  return __builtin_amdgcn_perm(TH[r], TL[r], sel);
}

__global__ __launch_bounds__(512, 4) void k_gemm(const uint8_t* __restrict__ Au,
                                                 const uint8_t* __restrict__ Av,
                                                 const int8_t* __restrict__ Pu,
                                                 const int8_t* __restrict__ Pv,
                                                 const int* __restrict__ Nu,
                                                 const int* __restrict__ Nv,
                                                 __hip_bfloat16* __restrict__ Hp) {
  __shared__ __attribute__((aligned(16))) char Bls[2][40960];

  const int bid = blockIdx.x;
  const int side = bid & 1, bn = (bid >> 1) & 1, ks = (bid >> 2) & 3;
  const int bm = bid >> 4;                          // 0..31
  const uint8_t* __restrict__ A8 = side ? Av : Au;
  const int8_t* __restrict__ P  = side ? Pv : Pu;
  const int* __restrict__ cnt = side ? Nv : Nu;
  const int kbeg = ks * 1024;                       // 16 steps of 64

  const int t = threadIdx.x;
  const int w = t >> 6, l = t & 63;
  const int l15 = l & 15, l4 = l >> 4;
  const int rowg = w >> 2, colw = w & 3;

  // ---- staging map: 5 gload_lds per wave; instr n = w*5+i covers 1KB =
  // (r = n>>3, cols chunk*16..+16); lane l -> col chunk*16+(l>>2), unit l&3;
  // source unit j = (l&3) ^ ((l>>3)&3)  [key (col>>1)&3 = (l>>3)&3]
  uint32_t soff[5], ldst[5];
  {
    const uint32_t jsrc = (uint32_t)((l & 3) ^ ((l >> 3) & 3));
#pragma unroll
    for (int i = 0; i < 5; ++i) {
      const int n = w * 5 + i;
      const int r = n >> 3, chunk = n & 7;
      const int colg = bn * 128 + chunk * 16 + (l >> 2);
      soff[i] = (uint32_t)(r * 256 + colg) * KP + jsrc * 16u;
      ldst[i] = (uint32_t)(n << 10);
    }
  }
#define STAGE(bi, kk) { _Pragma("unroll") \
  for (int i_ = 0; i_ < 5; ++i_) \
    GLOAD_LDS(P + soff[i_] + (uint32_t)(kk), &Bls[bi][0] + ldst[i_]); }

  // ---- B read base: col = colw*32 + cslot*16 + l15, unit l4 ^ ((l15>>1)&3)
  const uint32_t rbase = (uint32_t)(colw * 2048 + l15 * 64) +
                         ((uint32_t)(l4 ^ ((l15 >> 1) & 3)) << 4);

  // ---- A: packed byte offset per 16-row frag g
  uint32_t paoff[4];
#pragma unroll
  for (int g = 0; g < 4; ++g)
    paoff[g] = (uint32_t)(bm * 128 + rowg * 64 + g * 16 + l15) * KPH + l4 * 8;

  i32x4 acc[4][2] = {};
  uint2 aC[4], aN[4];

  // prologue
  STAGE(0, kbeg);
#pragma unroll
  for (int g = 0; g < 4; ++g)
    aC[g] = *(const uint2*)(A8 + paoff[g] + (kbeg >> 1));
  __syncthreads();

  for (int st = 0; st < 16; ++st) {
    const int kk = kbeg + st * 64;
    if (st < 15) {
      STAGE((st & 1) ^ 1, kk + 64);
#pragma unroll
      for (int g = 0; g < 4; ++g)
        aN[g] = *(const uint2*)(A8 + paoff[g] + ((kk + 64) >> 1));
    }
    // unpack nibbles -> 4 byte-dwords per frag (k-order matches P permutation)
    uint32_t ud[4][4];
#pragma unroll
    for (int g = 0; g < 4; ++g) {
      ud[g][0] = aC[g].x & 0x0F0F0F0Fu;
      ud[g][1] = (aC[g].x >> 4) & 0x0F0F0F0Fu;
      ud[g][2] = aC[g].y & 0x0F0F0F0Fu;
      ud[g][3] = (aC[g].y >> 4) & 0x0F0F0F0Fu;
    }
    const char* lb = &Bls[st & 1][0];
    __builtin_amdgcn_s_setprio(1);
#pragma unroll
    for (int r = 0; r < 5; ++r) {
      const uint4 B0 = *(const uint4*)(lb + r * 8192 + rbase);
      const uint4 B1 = *(const uint4*)(lb + r * 8192 + rbase + 1024);
#pragma unroll
      for (int g = 0; g < 4; ++g) {
        uint4 af;
        af.x = ohp(ud[g][0], r); af.y = ohp(ud[g][1], r);
        af.z = ohp(ud[g][2], r); af.w = ohp(ud[g][3], r);
        const i32x4 a4 = __builtin_bit_cast(i32x4, af);
        acc[g][0] = __builtin_amdgcn_mfma_i32_16x16x64_i8(
            a4, __builtin_bit_cast(i32x4, B0), acc[g][0], 0, 0, 0);
        acc[g][1] = __builtin_amdgcn_mfma_i32_16x16x64_i8(
            a4, __builtin_bit_cast(i32x4, B1), acc[g][1], 0, 0, 0);
      }
    }
    __builtin_amdgcn_s_setprio(0);
#pragma unroll
    for (int g = 0; g < 4; ++g) aC[g] = aN[g];
    __syncthreads();
  }

  // epilogue: scale by rsqrt(cnt)/256, store bf16 partial (relu deferred)
  __hip_bfloat16* hp = Hp + (size_t)(ks * 2 + side) * HP_STRIDE;
#pragma unroll
  for (int g = 0; g < 4; ++g) {
    const int rowb = bm * 128 + rowg * 64 + g * 16 + l4 * 4;
#pragma unroll
    for (int c = 0; c < 2; ++c) {
      const int ocol = bn * 128 + colw * 32 + c * 16 + l15;
#pragma unroll
      for (int q = 0; q < 4; ++q) {
        const int orow = rowb + q;
        if (orow < 4000) {
          const int cv = cnt[orow];
          const float s = cv > 0 ? rsqrtf((float)cv) * (1.0f / 256.0f) : 0.f;
          hp[(size_t)orow * 256 + ocol] = __float2bfloat16((float)acc[g][c][q] * s);
        }
      }
    }
  }
#undef STAGE
}

// ---------------------------------------------------------------------------
// K4: fused stage 2 (MFMA). Hsum = relu(sum of 4 partials) (already scaled).
//   F = relu(sf@W1^T + b1);  out = relu(Hsum@dW^T + F@W2^T)
// grid 250 = 2 sides x 125, block 128.
// ---------------------------------------------------------------------------
__global__ __launch_bounds__(128) void k_out(const __hip_bfloat16* __restrict__ Hp,
                                             const float* __restrict__ usf,
                                             const float* __restrict__ vsf,
                                             const float* __restrict__ dW,
                                             const float* __restrict__ uW1,
                                             const float* __restrict__ ub1,
                                             const float* __restrict__ uW2,
                                             const float* __restrict__ vW1,
                                             const float* __restrict__ vb1,
                                             const float* __restrict__ vW2,
                                             float* __restrict__ out) {
  const int bid = blockIdx.x;
  const int side = bid / 125, rb = bid % 125;
  const int t = threadIdx.x, w = t >> 6, l = t & 63;
  const int l15 = l & 15, l4 = l >> 4;
  const int r0 = rb * 32 + w * 16;
  const float* __restrict__ sf = side ? vsf : usf;
  const float* __restrict__ W1 = side ? vW1 : uW1;
  const float* __restrict__ b1 = side ? vb1 : ub1;
  const float* __restrict__ W2 = side ? vW2 : uW2;
  const __hip_bfloat16* __restrict__ hp = Hp + (size_t)side * HP_STRIDE;

  const int myrow = r0 + l15;

  __shared__ __hip_bfloat16 lf[2][16][72];

  // ---- Phase A: F = relu(sf @ W1^T + b1) ----
  f32x4 fA[4] = {};
#pragma unroll
  for (int kk = 0; kk < 128; kk += 32) {
    const float* ps = sf + (size_t)myrow * 128 + kk + 8 * l4;
    const bf16x8 af = cvt8(*(const f32x4*)ps, *(const f32x4*)(ps + 4));
#pragma unroll
    for (int c = 0; c < 4; ++c) {
      const float* pw = W1 + (size_t)(c * 16 + l15) * 128 + kk + 8 * l4;
      const bf16x8 bf = cvt8(*(const f32x4*)pw, *(const f32x4*)(pw + 4));
      fA[c] = __builtin_amdgcn_mfma_f32_16x16x32_bf16(af, bf, fA[c], 0, 0, 0);
    }
  }
#pragma unroll
  for (int c = 0; c < 4; ++c) {
    const float bv = b1[c * 16 + l15];
#pragma unroll
    for (int reg = 0; reg < 4; ++reg) {
      float v = fA[c][reg] + bv;
      lf[w][l4 * 4 + reg][c * 16 + l15] = __float2bfloat16(v > 0.f ? v : 0.f);
    }
  }
  __syncthreads();

  // ---- Phase B: out = relu(Hsum@dW^T + F@W2^T) ----
  f32x4 oA[5] = {};
  const __hip_bfloat16* hbase = hp + (size_t)myrow * 256 + 8 * l4;
#pragma unroll
  for (int kk = 0; kk < 256; kk += 32) {
    const bf16x8 q0 = *(const bf16x8*)(hbase + kk);
    const bf16x8 q1 = *(const bf16x8*)(hbase + 2 * HP_STRIDE + kk);
    const bf16x8 q2 = *(const bf16x8*)(hbase + 4 * HP_STRIDE + kk);
    const bf16x8 q3 = *(const bf16x8*)(hbase + 6 * HP_STRIDE + kk);
    bf16x8 af;
#pragma unroll
    for (int j = 0; j < 8; ++j) {
      float hv = b2f(q0[j]) + b2f(q1[j]) + b2f(q2[j]) + b2f(q3[j]);
      af[j] = f2b(hv > 0.f ? hv : 0.f);
    }
#pragma unroll
    for (int c = 0; c < 5; ++c) {
      int oc = c * 16 + l15; if (oc > 74) oc = 74;   // clamp, stores guarded
      const float* pd = dW + (size_t)oc * 256 + kk + 8 * l4;
      const bf16x8 bf = cvt8(*(const f32x4*)pd, *(const f32x4*)(pd + 4));
      oA[c] = __builtin_amdgcn_mfma_f32_16x16x32_bf16(af, bf, oA[c], 0, 0, 0);
    }
  }
#pragma unroll
  for (int kk = 0; kk < 64; kk += 32) {
    const bf16x8 af = *(const bf16x8*)(&lf[w][l15][kk + 8 * l4]);
#pragma unroll
    for (int c = 0; c < 5; ++c) {
      int oc = c * 16 + l15; if (oc > 74) oc = 74;
      const float* pw = W2 + (size_t)oc * 64 + kk + 8 * l4;
      const bf16x8 bf = cvt8(*(const f32x4*)pw, *(const f32x4*)(pw + 4));
      oA[c] = __builtin_amdgcn_mfma_f32_16x16x32_bf16(af, bf, oA[c], 0, 0, 0);
    }
  }
  float* po = out + (size_t)side * (4000 * 75);
#pragma unroll
  for (int c = 0; c < 5; ++c) {
    const int oc = c * 16 + l15;
    if (oc < 75) {
#pragma unroll
      for (int reg = 0; reg < 4; ++reg) {
        const int orow = r0 + l4 * 4 + reg;
        const float v = oA[c][reg];
        po[(size_t)orow * 75 + oc] = v > 0.f ? v : 0.f;
      }
    }
  }
}

// ---------------------------------------------------------------------------
extern "C" void kernel_launch(void* const* d_in, const int* in_sizes, int n_in,
                              void* d_out, int out_size, void* d_ws, size_t ws_size,
                              hipStream_t stream) {
  const int* adj = (const int*)d_in[0];
  const float* usf = (const float*)d_in[1];
  const float* vsf = (const float*)d_in[2];
  const float* msgW = (const float*)d_in[3];
  const float* dW = (const float*)d_in[4];
  const float* uW1 = (const float*)d_in[5];
  const float* ub1 = (const float*)d_in[6];
  const float* uW2 = (const float*)d_in[7];
  const float* vW1 = (const float*)d_in[8];
  const float* vb1 = (const float*)d_in[9];
  const float* vW2 = (const float*)d_in[10];
  float* out = (float*)d_out;

  char* w = (char*)d_ws;
  const size_t A_BYTES = (size_t)4096 * KPH;           // 8,388,608 (packed)
  const size_t P_BYTES = (size_t)RR * MM * KP;         // 5,242,880 (int8)
  const size_t HP_BYTES = (size_t)8 * HP_STRIDE * 2;   // 16,384,000 (bf16)
  int* Nu = (int*)w;
  int* Nv = (int*)(w + 16384);
  uint8_t* Au = (uint8_t*)(w + 32768);
  uint8_t* Av = Au + A_BYTES;
  int8_t* Pu = (int8_t*)(w + 32768 + 2 * A_BYTES);
  int8_t* Pv = Pu + P_BYTES;
  __hip_bfloat16* Hp = (__hip_bfloat16*)(w + 32768 + 2 * A_BYTES + 2 * P_BYTES);
  const size_t need = 32768 + 2 * A_BYTES + 2 * P_BYTES + HP_BYTES;  // 43,679,744
  if (ws_size < need) return;

  hipMemsetAsync(w, 0, 32768, stream);
  k_trans<<<dim3(64, 64), 256, 0, stream>>>(adj, Au, Av, Nu, Nv);
  k_pbuild<<<1280, 256, 0, stream>>>(msgW, Nu, Nv, Pu, Pv);
  k_gemm<<<512, 512, 0, stream>>>(Au, Av, Pu, Pv, Nu, Nv, Hp);
  k_out<<<250, 128, 0, stream>>>(Hp, usf, vsf, dW, uW1, ub1, uW2, vW1, vb1, vW2,
                                 out);
}

// Round 8
// 113.495 us; speedup vs baseline: 1.4361x; 1.0290x over previous
//
#include <hip/hip_runtime.h>
#include <hip/hip_bf16.h>
#include <stdint.h>

// Problem constants
#define NU 4000
#define NI 4000
#define RR 5
#define MM 256
#define OUTD 75
#define FDIM 128
#define KP 4096                 // padded K length (P rows)
#define KPH 2048                // packed A row bytes (KP/2)
#define HP_STRIDE 1024000       // 4000*256 elements per partial

typedef float f32x4 __attribute__((ext_vector_type(4)));
typedef int   i32x4 __attribute__((ext_vector_type(4)));
typedef short bf16x8 __attribute__((ext_vector_type(8)));

static __device__ __forceinline__ short f2b(float x) {
  __hip_bfloat16 h = __float2bfloat16(x);
  return (short)__builtin_bit_cast(unsigned short, h);
}
static __device__ __forceinline__ float b2f(short x) {
  unsigned int u = ((unsigned int)(unsigned short)x) << 16;
  return __builtin_bit_cast(float, u);
}
static __device__ __forceinline__ bf16x8 cvt8(f32x4 a, f32x4 b) {
  bf16x8 r;
  r[0] = f2b(a[0]); r[1] = f2b(a[1]); r[2] = f2b(a[2]); r[3] = f2b(a[3]);
  r[4] = f2b(b[0]); r[5] = f2b(b[1]); r[6] = f2b(b[2]); r[7] = f2b(b[3]);
  return r;
}

// ---------------------------------------------------------------------------
// K1: adj -> nibble-packed int8 (both layouts; byte p = col 2p | col 2p+1 <<4)
//     + degree counts. grid (64,64), pad region written as 0. (proven R7)
// ---------------------------------------------------------------------------
__global__ __launch_bounds__(256) void k_trans(const int* __restrict__ adj,
                                               uint8_t* __restrict__ a8p,
                                               uint8_t* __restrict__ a8tp,
                                               int* __restrict__ Nu,
                                               int* __restrict__ Nv) {
  __shared__ int8_t lt[64][65];
  __shared__ int rowc[64];
  __shared__ int colp[4][64];
  const int i0 = blockIdx.x * 64;
  const int u0 = blockIdx.y * 64;
  const int t = threadIdx.x;
  const int w = t >> 6, lane = t & 63;
  int mycol = 0;
  for (int rep = 0; rep < 16; rep++) {
    const int r = rep * 4 + w;
    const int u = u0 + r, i = i0 + lane;
    int a = (u < NU && i < NI) ? adj[(size_t)u * NI + i] : 0;
    const int nz = (a > 0) ? 1 : 0;
    unsigned long long bal = __ballot(nz);
    if (lane == 0) rowc[r] = (int)__popcll(bal);
    mycol += nz;
    lt[lane][r] = (int8_t)a;
    const int nb = __shfl_down(a, 1);
    if (!(lane & 1))
      a8p[(size_t)u * KPH + (i0 >> 1) + (lane >> 1)] = (uint8_t)(a | (nb << 4));
  }
  colp[w][lane] = mycol;
  __syncthreads();
  for (int rep = 0; rep < 16; rep++) {
    const int r = rep * 4 + w;
    const int it = i0 + r;
    const int v = lt[r][lane];
    const int nb = __shfl_down(v, 1);
    if (!(lane & 1))
      a8tp[(size_t)it * KPH + (u0 >> 1) + (lane >> 1)] = (uint8_t)(v | (nb << 4));
  }
  if (t < 64) {
    const int cc = colp[0][t] + colp[1][t] + colp[2][t] + colp[3][t];
    if (i0 + t < NI && cc) atomicAdd(&Nv[i0 + t], cc);
    if (u0 + t < NU && rowc[t]) atomicAdd(&Nu[u0 + t], rowc[t]);
  }
}

// ---------------------------------------------------------------------------
// K2: P build (int8, x256 scale), vectorized: 8 consecutive k per thread,
// per-8 k-permutation folded into the byte pack (storage s holds original
// k = (s&~7)|((s&3)<<1)|((s>>2)&1)  ->  lo=[q0,q2,q4,q6], hi=[q1,q3,q5,q7]).
// ---------------------------------------------------------------------------
__global__ __launch_bounds__(256) void k_pbuild(const float* __restrict__ msgW,
                                                const int* __restrict__ Nu,
                                                const int* __restrict__ Nv,
                                                int8_t* __restrict__ Pu,
                                                int8_t* __restrict__ Pv) {
  const int b = blockIdx.x;                 // r*256 + m
  const float* src = msgW + (size_t)b * (NU + NI);
#pragma unroll
  for (int it = 0; it < 2; ++it) {
    const int base = (threadIdx.x + it * 256) * 8;     // 0..4088, 8-aligned
    uint32_t lou = 0, hiu = 0, lov = 0, hiv = 0;
    if (base < NU) {                                    // NU = 8*500: all-in or all-out
      const f32x4 v0 = *(const f32x4*)(src + base);
      const f32x4 v1 = *(const f32x4*)(src + base + 4);
      const f32x4 u0 = *(const f32x4*)(src + NU + base);
      const f32x4 u1 = *(const f32x4*)(src + NU + base + 4);
      const int4 cu0 = *(const int4*)(Nu + base);
      const int4 cu1 = *(const int4*)(Nu + base + 4);
      const int4 cv0 = *(const int4*)(Nv + base);
      const int4 cv1 = *(const int4*)(Nv + base + 4);
      float qv[8], qu[8];
      const int cus[8] = {cu0.x, cu0.y, cu0.z, cu0.w, cu1.x, cu1.y, cu1.z, cu1.w};
      const int cvs[8] = {cv0.x, cv0.y, cv0.z, cv0.w, cv1.x, cv1.y, cv1.z, cv1.w};
      const float vs[8] = {v0[0], v0[1], v0[2], v0[3], v1[0], v1[1], v1[2], v1[3]};
      const float us[8] = {u0[0], u0[1], u0[2], u0[3], u1[0], u1[1], u1[2], u1[3]};
#pragma unroll
      for (int j = 0; j < 8; ++j) {
        const float su = cus[j] > 0 ? rsqrtf((float)cus[j]) * 256.0f : 0.f;
        const float sv = cvs[j] > 0 ? rsqrtf((float)cvs[j]) * 256.0f : 0.f;
        qv[j] = fminf(fmaxf(vs[j] * su, -127.f), 127.f);
        qu[j] = fminf(fmaxf(us[j] * sv, -127.f), 127.f);
      }
      uint32_t bv[8], bu[8];
#pragma unroll
      for (int j = 0; j < 8; ++j) {
        bv[j] = (uint32_t)(uint8_t)(int8_t)__float2int_rn(qv[j]);
        bu[j] = (uint32_t)(uint8_t)(int8_t)__float2int_rn(qu[j]);
      }
      lov = bv[0] | (bv[2] << 8) | (bv[4] << 16) | (bv[6] << 24);
      hiv = bv[1] | (bv[3] << 8) | (bv[5] << 16) | (bv[7] << 24);
      lou = bu[0] | (bu[2] << 8) | (bu[4] << 16) | (bu[6] << 24);
      hiu = bu[1] | (bu[3] << 8) | (bu[5] << 16) | (bu[7] << 24);
    }
    *(uint2*)(Pv + (size_t)b * KP + base) = make_uint2(lov, hiv);
    *(uint2*)(Pu + (size_t)b * KP + base) = make_uint2(lou, hiu);
  }
}

// ---------------------------------------------------------------------------
// K3: one-hot i8 MFMA GEMM, 5-phase interleaved schedule (T3 adapted).
//  Per step: A-prefetch first; then 5 phases {2 ds_read (B of r), 1 gload_lds
//  stage for next tile, one-hot perms, 8 MFMA, sched_barrier pin}; one
//  vmcnt(0)+s_barrier per step. Waves drift across phases -> LDS latency
//  overlaps other waves' MFMA instead of the post-barrier read storm.
//  Geometry as R7: 512 thr = 8 waves (2 rowg x 4 colw), tile 128x128, BK=64,
//  16 steps, grid 512 (2 blocks/CU), LDS 2x40KB zero-conflict swizzle.
// ---------------------------------------------------------------------------
#define GLOAD_LDS(g, s) __builtin_amdgcn_global_load_lds( \
    (const __attribute__((address_space(1))) uint32_t*)(g), \
    (__attribute__((address_space(3))) uint32_t*)(s), 16, 0, 0)

static __device__ __forceinline__ uint32_t ohp(uint32_t sel, int r) {
  // one-hot i8: result byte = 0x01 iff input byte == r+1 (inputs 0..5)
  const uint32_t TL[5] = {0x00000100u, 0x00010000u, 0x01000000u, 0u, 0u};
  const uint32_t TH[5] = {0u, 0u, 0u, 0x00000001u, 0x00000100u};
  return __builtin_amdgcn_perm(TH[r], TL[r], sel);
}

__global__ __launch_bounds__(512, 4) void k_gemm(const uint8_t* __restrict__ Au,
                                                 const uint8_t* __restrict__ Av,
                                                 const int8_t* __restrict__ Pu,
                                                 const int8_t* __restrict__ Pv,
                                                 const int* __restrict__ Nu,
                                                 const int* __restrict__ Nv,
                                                 __hip_bfloat16* __restrict__ Hp) {
  __shared__ __attribute__((aligned(16))) char Bls[2][40960];

  const int bid = blockIdx.x;
  const int side = bid & 1, bn = (bid >> 1) & 1, ks = (bid >> 2) & 3;
  const int bm = bid >> 4;                          // 0..31
  const uint8_t* __restrict__ A8 = side ? Av : Au;
  const int8_t* __restrict__ P  = side ? Pv : Pu;
  const int* __restrict__ cnt = side ? Nv : Nu;
  const int kbeg = ks * 1024;                       // 16 steps of 64

  const int t = threadIdx.x;
  const int w = t >> 6, l = t & 63;
  const int l15 = l & 15, l4 = l >> 4;
  const int rowg = w >> 2, colw = w & 3;

  // staging map (proven R7): instr n = w*5+i covers 1KB = (r=n>>3, 16 cols);
  // lane l -> col chunk*16+(l>>2), source 16B unit j = (l&3) ^ ((l>>3)&3)
  uint32_t soff[5], ldst[5];
  {
    const uint32_t jsrc = (uint32_t)((l & 3) ^ ((l >> 3) & 3));
#pragma unroll
    for (int i = 0; i < 5; ++i) {
      const int n = w * 5 + i;
      const int r = n >> 3, chunk = n & 7;
      const int colg = bn * 128 + chunk * 16 + (l >> 2);
      soff[i] = (uint32_t)(r * 256 + colg) * KP + jsrc * 16u;
      ldst[i] = (uint32_t)(n << 10);
    }
  }
#define STAGE(bi, kk) { _Pragma("unroll") \
  for (int i_ = 0; i_ < 5; ++i_) \
    GLOAD_LDS(P + soff[i_] + (uint32_t)(kk), &Bls[bi][0] + ldst[i_]); }

  // B read base: col = colw*32 + cslot*16 + l15, unit l4 ^ ((l15>>1)&3)
  const uint32_t rbase = (uint32_t)(colw * 2048 + l15 * 64) +
                         ((uint32_t)(l4 ^ ((l15 >> 1) & 3)) << 4);

  // A: packed byte offset per 16-row frag g
  uint32_t paoff[4];
#pragma unroll
  for (int g = 0; g < 4; ++g)
    paoff[g] = (uint32_t)(bm * 128 + rowg * 64 + g * 16 + l15) * KPH + l4 * 8;

  i32x4 acc[4][2] = {};
  uint2 aC[4], aN[4];

  // prologue
  STAGE(0, kbeg);
#pragma unroll
  for (int g = 0; g < 4; ++g)
    aC[g] = *(const uint2*)(A8 + paoff[g] + (kbeg >> 1));
  __syncthreads();

#define STEP(st, MORE) { \
  const int kk_ = kbeg + (st) * 64; \
  if (MORE) { _Pragma("unroll") \
    for (int g_ = 0; g_ < 4; ++g_) \
      aN[g_] = *(const uint2*)(A8 + paoff[g_] + ((kk_ + 64) >> 1)); } \
  uint32_t ud[4][4]; \
  _Pragma("unroll") \
  for (int g_ = 0; g_ < 4; ++g_) { \
    ud[g_][0] = aC[g_].x & 0x0F0F0F0Fu; \
    ud[g_][1] = (aC[g_].x >> 4) & 0x0F0F0F0Fu; \
    ud[g_][2] = aC[g_].y & 0x0F0F0F0Fu; \
    ud[g_][3] = (aC[g_].y >> 4) & 0x0F0F0F0Fu; } \
  const char* lb_ = &Bls[(st) & 1][0]; \
  char* nb_ = &Bls[((st) & 1) ^ 1][0]; \
  _Pragma("unroll") \
  for (int r_ = 0; r_ < 5; ++r_) { \
    const uint4 B0 = *(const uint4*)(lb_ + r_ * 8192 + rbase); \
    const uint4 B1 = *(const uint4*)(lb_ + r_ * 8192 + rbase + 1024); \
    if (MORE) GLOAD_LDS(P + soff[r_] + (uint32_t)(kk_ + 64), nb_ + ldst[r_]); \
    uint4 af[4]; \
    _Pragma("unroll") \
    for (int g_ = 0; g_ < 4; ++g_) { \
      af[g_].x = ohp(ud[g_][0], r_); af[g_].y = ohp(ud[g_][1], r_); \
      af[g_].z = ohp(ud[g_][2], r_); af[g_].w = ohp(ud[g_][3], r_); } \
    __builtin_amdgcn_s_setprio(1); \
    _Pragma("unroll") \
    for (int g_ = 0; g_ < 4; ++g_) { \
      const i32x4 a4_ = __builtin_bit_cast(i32x4, af[g_]); \
      acc[g_][0] = __builtin_amdgcn_mfma_i32_16x16x64_i8( \
          a4_, __builtin_bit_cast(i32x4, B0), acc[g_][0], 0, 0, 0); \
      acc[g_][1] = __builtin_amdgcn_mfma_i32_16x16x64_i8( \
          a4_, __builtin_bit_cast(i32x4, B1), acc[g_][1], 0, 0, 0); } \
    __builtin_amdgcn_s_setprio(0); \
    __builtin_amdgcn_sched_barrier(0); } \
  if (MORE) { _Pragma("unroll") \
    for (int g_ = 0; g_ < 4; ++g_) aC[g_] = aN[g_]; } \
  asm volatile("s_waitcnt vmcnt(0)" ::: "memory"); \
  __builtin_amdgcn_s_barrier(); }

  for (int st = 0; st < 15; ++st) STEP(st, 1)
  STEP(15, 0)
#undef STEP

  // epilogue: scale by rsqrt(cnt)/256, store bf16 partial (relu deferred)
  __hip_bfloat16* hp = Hp + (size_t)(ks * 2 + side) * HP_STRIDE;
#pragma unroll
  for (int g = 0; g < 4; ++g) {
    const int rowb = bm * 128 + rowg * 64 + g * 16 + l4 * 4;
#pragma unroll
    for (int c = 0; c < 2; ++c) {
      const int ocol = bn * 128 + colw * 32 + c * 16 + l15;
#pragma unroll
      for (int q = 0; q < 4; ++q) {
        const int orow = rowb + q;
        if (orow < 4000) {
          const int cv = cnt[orow];
          const float s = cv > 0 ? rsqrtf((float)cv) * (1.0f / 256.0f) : 0.f;
          hp[(size_t)orow * 256 + ocol] = __float2bfloat16((float)acc[g][c][q] * s);
        }
      }
    }
  }
#undef STAGE
}

// ---------------------------------------------------------------------------
// K4: fused stage 2 (MFMA). Hsum = relu(sum of 4 partials) (already scaled).
//   F = relu(sf@W1^T + b1);  out = relu(Hsum@dW^T + F@W2^T)
// grid 500 = 2 sides x 250 (16 rows each), block 64 (1 wave).
// ---------------------------------------------------------------------------
__global__ __launch_bounds__(64) void k_out(const __hip_bfloat16* __restrict__ Hp,
                                            const float* __restrict__ usf,
                                            const float* __restrict__ vsf,
                                            const float* __restrict__ dW,
                                            const float* __restrict__ uW1,
                                            const float* __restrict__ ub1,
                                            const float* __restrict__ uW2,
                                            const float* __restrict__ vW1,
                                            const float* __restrict__ vb1,
                                            const float* __restrict__ vW2,
                                            float* __restrict__ out) {
  const int bid = blockIdx.x;
  const int side = bid / 250, rb = bid % 250;
  const int l = threadIdx.x & 63;
  const int l15 = l & 15, l4 = l >> 4;
  const int r0 = rb * 16;
  const float* __restrict__ sf = side ? vsf : usf;
  const float* __restrict__ W1 = side ? vW1 : uW1;
  const float* __restrict__ b1 = side ? vb1 : ub1;
  const float* __restrict__ W2 = side ? vW2 : uW2;
  const __hip_bfloat16* __restrict__ hp = Hp + (size_t)side * HP_STRIDE;

  const int myrow = r0 + l15;

  __shared__ __hip_bfloat16 lf[16][72];

  // ---- Phase A: F = relu(sf @ W1^T + b1) ----
  f32x4 fA[4] = {};
#pragma unroll
  for (int kk = 0; kk < 128; kk += 32) {
    const float* ps = sf + (size_t)myrow * 128 + kk + 8 * l4;
    const bf16x8 af = cvt8(*(const f32x4*)ps, *(const f32x4*)(ps + 4));
#pragma unroll
    for (int c = 0; c < 4; ++c) {
      const float* pw = W1 + (size_t)(c * 16 + l15) * 128 + kk + 8 * l4;
      const bf16x8 bf = cvt8(*(const f32x4*)pw, *(const f32x4*)(pw + 4));
      fA[c] = __builtin_amdgcn_mfma_f32_16x16x32_bf16(af, bf, fA[c], 0, 0, 0);
    }
  }
#pragma unroll
  for (int c = 0; c < 4; ++c) {
    const float bv = b1[c * 16 + l15];
#pragma unroll
    for (int reg = 0; reg < 4; ++reg) {
      float v = fA[c][reg] + bv;
      lf[l4 * 4 + reg][c * 16 + l15] = __float2bfloat16(v > 0.f ? v : 0.f);
    }
  }
  __syncthreads();

  // ---- Phase B: out = relu(Hsum@dW^T + F@W2^T) ----
  f32x4 oA[5] = {};
  const __hip_bfloat16* hbase = hp + (size_t)myrow * 256 + 8 * l4;
#pragma unroll
  for (int kk = 0; kk < 256; kk += 32) {
    const bf16x8 q0 = *(const bf16x8*)(hbase + kk);
    const bf16x8 q1 = *(const bf16x8*)(hbase + 2 * HP_STRIDE + kk);
    const bf16x8 q2 = *(const bf16x8*)(hbase + 4 * HP_STRIDE + kk);
    const bf16x8 q3 = *(const bf16x8*)(hbase + 6 * HP_STRIDE + kk);
    bf16x8 af;
#pragma unroll
    for (int j = 0; j < 8; ++j) {
      float hv = b2f(q0[j]) + b2f(q1[j]) + b2f(q2[j]) + b2f(q3[j]);
      af[j] = f2b(hv > 0.f ? hv : 0.f);
    }
#pragma unroll
    for (int c = 0; c < 5; ++c) {
      int oc = c * 16 + l15; if (oc > 74) oc = 74;   // clamp, stores guarded
      const float* pd = dW + (size_t)oc * 256 + kk + 8 * l4;
      const bf16x8 bf = cvt8(*(const f32x4*)pd, *(const f32x4*)(pd + 4));
      oA[c] = __builtin_amdgcn_mfma_f32_16x16x32_bf16(af, bf, oA[c], 0, 0, 0);
    }
  }
#pragma unroll
  for (int kk = 0; kk < 64; kk += 32) {
    const bf16x8 af = *(const bf16x8*)(&lf[l15][kk + 8 * l4]);
#pragma unroll
    for (int c = 0; c < 5; ++c) {
      int oc = c * 16 + l15; if (oc > 74) oc = 74;
      const float* pw = W2 + (size_t)oc * 64 + kk + 8 * l4;
      const bf16x8 bf = cvt8(*(const f32x4*)pw, *(const f32x4*)(pw + 4));
      oA[c] = __builtin_amdgcn_mfma_f32_16x16x32_bf16(af, bf, oA[c], 0, 0, 0);
    }
  }
  float* po = out + (size_t)side * (4000 * 75);
#pragma unroll
  for (int c = 0; c < 5; ++c) {
    const int oc = c * 16 + l15;
    if (oc < 75) {
#pragma unroll
      for (int reg = 0; reg < 4; ++reg) {
        const int orow = r0 + l4 * 4 + reg;
        const float v = oA[c][reg];
        po[(size_t)orow * 75 + oc] = v > 0.f ? v : 0.f;
      }
    }
  }
}

// ---------------------------------------------------------------------------
extern "C" void kernel_launch(void* const* d_in, const int* in_sizes, int n_in,
                              void* d_out, int out_size, void* d_ws, size_t ws_size,
                              hipStream_t stream) {
  const int* adj = (const int*)d_in[0];
  const float* usf = (const float*)d_in[1];
  const float* vsf = (const float*)d_in[2];
  const float* msgW = (const float*)d_in[3];
  const float* dW = (const float*)d_in[4];
  const float* uW1 = (const float*)d_in[5];
  const float* ub1 = (const float*)d_in[6];
  const float* uW2 = (const float*)d_in[7];
  const float* vW1 = (const float*)d_in[8];
  const float* vb1 = (const float*)d_in[9];
  const float* vW2 = (const float*)d_in[10];
  float* out = (float*)d_out;

  char* w = (char*)d_ws;
  const size_t A_BYTES = (size_t)4096 * KPH;           // 8,388,608 (packed)
  const size_t P_BYTES = (size_t)RR * MM * KP;         // 5,242,880 (int8)
  const size_t HP_BYTES = (size_t)8 * HP_STRIDE * 2;   // 16,384,000 (bf16)
  int* Nu = (int*)w;
  int* Nv = (int*)(w + 16384);
  uint8_t* Au = (uint8_t*)(w + 32768);
  uint8_t* Av = Au + A_BYTES;
  int8_t* Pu = (int8_t*)(w + 32768 + 2 * A_BYTES);
  int8_t* Pv = Pu + P_BYTES;
  __hip_bfloat16* Hp = (__hip_bfloat16*)(w + 32768 + 2 * A_BYTES + 2 * P_BYTES);
  const size_t need = 32768 + 2 * A_BYTES + 2 * P_BYTES + HP_BYTES;  // 43,679,744
  if (ws_size < need) return;

  hipMemsetAsync(w, 0, 32768, stream);
  k_trans<<<dim3(64, 64), 256, 0, stream>>>(adj, Au, Av, Nu, Nv);
  k_pbuild<<<1280, 256, 0, stream>>>(msgW, Nu, Nv, Pu, Pv);
  k_gemm<<<512, 512, 0, stream>>>(Au, Av, Pu, Pv, Nu, Nv, Hp);
  k_out<<<500, 64, 0, stream>>>(Hp, usf, vsf, dW, uW1, ub1, uW2, vW1, vb1, vW2,
                                out);
}